// Round 13
// baseline (202.020 us; speedup 1.0000x reference)
//
#include <hip/hip_runtime.h>

typedef __attribute__((ext_vector_type(8))) short bf16x8;
typedef __attribute__((ext_vector_type(4))) float f32x4;

#define D_IN 256
#define D_OUT 256
#define G_ROWS 8           // dst rows per wave in agg
#define CAP 32             // edge slots per dst row (max deg ~22 for Poisson(8))

static __device__ __forceinline__ unsigned short f2bf(float f) {
    union { float f; unsigned int u; } x; x.f = f;
    unsigned int r = (x.u + 0x7FFFu + ((x.u >> 16) & 1u)) >> 16;
    return (unsigned short)r;
}
static __device__ __forceinline__ float bf2f(unsigned short u) {
    union { unsigned int i; float f; } x; x.i = ((unsigned int)u) << 16; return x.f;
}

// async global->LDS: lds dest = UNIFORM base (HW adds lane*16); global src = per-lane
#define GLOAD16(gp, lp) __builtin_amdgcn_global_load_lds(                    \
    (const __attribute__((address_space(1))) void*)(gp),                     \
    (__attribute__((address_space(3))) void*)(lp), 16, 0, 0)
// non-temporal (aux=2): evict-first, keeps L3 for Xs reuse
#define GLOAD16NT(gp, lp) __builtin_amdgcn_global_load_lds(                  \
    (const __attribute__((address_space(1))) void*)(gp),                     \
    (__attribute__((address_space(3))) void*)(lp), 16, 0, 2)

// ---------------- zero cursor + pack BOTH W-half fragments ----------------
// wfrag (K=256 each): wf[((nt*8+kk)*64+l)*8+j] = bf16(W[s*256 + kk*32+(l>>4)*8+j][nt*16+(l&15)])
__global__ void zero_wfrag_kernel(int* __restrict__ cursor, int n, int zblocks,
                                  const float* __restrict__ W,
                                  unsigned short* __restrict__ wfs,
                                  unsigned short* __restrict__ wfe) {
    int b = blockIdx.x;
    if (b < zblocks) {
        int i = b * 256 + threadIdx.x;
        if (i < n) cursor[i] = 0;
        return;
    }
    int s = (b - zblocks) >> 5;                      // 0: Ws, 1: We
    int t = ((b - zblocks) & 31) * 256 + threadIdx.x; // 0..8191
    int l  = t & 63;
    int kk = (t >> 6) & 7;
    int nt = t >> 9;
    int c  = nt * 16 + (l & 15);
    int kb = s * 256 + kk * 32 + (l >> 4) * 8;
    union { unsigned short u[8]; uint4 v; } pk;
#pragma unroll
    for (int j = 0; j < 8; ++j) pk.u[j] = f2bf(W[(size_t)(kb + j) * D_OUT + c]);
    unsigned short* wf = s ? wfe : wfs;
    *reinterpret_cast<uint4*>(&wf[(size_t)t * 8]) = pk.v;
}

// ---------------- combo: bucket scatter (blocks < SB) + xs_gemm (rest) ----------------
__global__ __launch_bounds__(256) void combo_kernel(
    const int* __restrict__ dst, const int* __restrict__ src_idx,
    int* __restrict__ cursor, int2* __restrict__ rec, int E, int SB,
    const float* __restrict__ src_feats, const unsigned short* __restrict__ wfs,
    unsigned short* __restrict__ Xs, int n_src)
{
    __shared__ __align__(16) float As[32 * 256];   // 32 KB (xs part only)

    if (blockIdx.x < SB) {
        int e2 = (blockIdx.x * 256 + threadIdx.x) * 2;
        if (e2 + 1 < E) {
            int2 d = *reinterpret_cast<const int2*>(&dst[e2]);
            int2 s = *reinterpret_cast<const int2*>(&src_idx[e2]);
            int p0 = atomicAdd(&cursor[d.x], 1);
            if (p0 < CAP) rec[(size_t)d.x * CAP + p0] = make_int2(e2, s.x);
            int p1 = atomicAdd(&cursor[d.y], 1);
            if (p1 < CAP) rec[(size_t)d.y * CAP + p1] = make_int2(e2 + 1, s.y);
        } else if (e2 < E) {
            int d = dst[e2];
            int p = atomicAdd(&cursor[d], 1);
            if (p < CAP) rec[(size_t)d * CAP + p] = make_int2(e2, src_idx[e2]);
        }
        return;
    }

    const int wv = threadIdx.x >> 6;
    const int ln = threadIdx.x & 63;
    const int lrow = ln & 15;
    const int lgrp = ln >> 4;
    const int base = (blockIdx.x - SB) * 32;

#pragma unroll
    for (int q = 0; q < 8; ++q) {
        int r = q * 4 + wv;
        int gr = base + r; if (gr >= n_src) gr = n_src - 1;
        GLOAD16(src_feats + (size_t)gr * D_IN + ((ln ^ (r & 7)) * 4),
                (char*)As + r * 1024);
    }
    asm volatile("s_waitcnt vmcnt(0)" ::: "memory");
    __builtin_amdgcn_s_barrier();
    __builtin_amdgcn_sched_barrier(0);

    f32x4 acc[2][4];
#pragma unroll
    for (int m = 0; m < 2; ++m)
#pragma unroll
        for (int n = 0; n < 4; ++n) acc[m][n] = (f32x4)(0.0f);

#pragma unroll
    for (int kk = 0; kk < 8; ++kk) {
        bf16x8 A[2];
#pragma unroll
        for (int m = 0; m < 2; ++m) {
            int r = m * 16 + lrow;
            int pi = kk * 4 + lgrp;
            int g0 = (2 * pi) ^ (r & 7);
            int g1 = (2 * pi + 1) ^ (r & 7);
            float4 f0 = *reinterpret_cast<const float4*>((const char*)As + r * 1024 + g0 * 16);
            float4 f1 = *reinterpret_cast<const float4*>((const char*)As + r * 1024 + g1 * 16);
            union { unsigned short u[8]; bf16x8 v; } pk;
            pk.u[0] = f2bf(f0.x); pk.u[1] = f2bf(f0.y); pk.u[2] = f2bf(f0.z); pk.u[3] = f2bf(f0.w);
            pk.u[4] = f2bf(f1.x); pk.u[5] = f2bf(f1.y); pk.u[6] = f2bf(f1.z); pk.u[7] = f2bf(f1.w);
            A[m] = pk.v;
        }
#pragma unroll
        for (int n = 0; n < 4; ++n) {
            int nt = wv * 4 + n;
            bf16x8 B = *reinterpret_cast<const bf16x8*>(&wfs[(((size_t)nt * 8 + kk) * 64 + ln) * 8]);
#pragma unroll
            for (int m = 0; m < 2; ++m)
                acc[m][n] = __builtin_amdgcn_mfma_f32_16x16x32_bf16(A[m], B, acc[m][n], 0, 0, 0);
        }
    }

#pragma unroll
    for (int m = 0; m < 2; ++m) {
#pragma unroll
        for (int j = 0; j < 4; ++j) {
            int r = base + m * 16 + lgrp * 4 + j;
            if (r < n_src) {
#pragma unroll
                for (int n = 0; n < 4; ++n)
                    Xs[(size_t)r * D_OUT + wv * 64 + n * 16 + lrow] = f2bf(acc[m][n][j]);
            }
        }
    }
}

// ---------------- fused aggregate + GEMM ----------------
// Phase 1 (binning pipeline, identical to R12 agg): rows flush to REGISTERS (bf16-packed).
// Phase 2: regs -> LDS (unioned with dead phase-1 buffers), K=256 MFMA GEMM, epilogue.
__global__ __launch_bounds__(256) void agg_gemm_kernel(
    const unsigned short* __restrict__ Xs,
    const float* __restrict__ edge_feats,
    const int2* __restrict__ rec,
    const int* __restrict__ cursor,
    const unsigned short* __restrict__ wfe,
    const float* __restrict__ bias,
    float* __restrict__ out,
    int n_dst)
{
    __shared__ __align__(16) char pool[32768];
    // phase 1 views:
    float (*fbe)[2][2][D_IN]      = (float(*)[2][2][D_IN])pool;                     // 16 KB
    unsigned short (*sxb)[2][512] = (unsigned short(*)[2][512])(pool + 16384);      //  8 KB
    int2 (*idb)[G_ROWS * CAP]     = (int2(*)[G_ROWS * CAP])(pool + 24576);          //  8 KB
    // phase 2 views (valid only after the post-loop __syncthreads):
    unsigned short* AsL = (unsigned short*)pool;            // 32 rows x 512 B, swizzled granules
    unsigned short* SxL = (unsigned short*)(pool + 16384);  // 32 rows x 512 B row-major

    const int wv = threadIdx.x >> 6;
    const int ln = threadIdx.x & 63;
    const int bbase = blockIdx.x * 32;
    const int rowbase = bbase + wv * G_ROWS;

    int cnt = 0;
    if (ln < G_ROWS) {
        int i = rowbase + ln;
        if (i < n_dst) { cnt = cursor[i]; if (cnt > CAP) cnt = CAP; }
    }
    int incl = cnt;
#pragma unroll
    for (int o = 1; o < 64; o <<= 1) { int u = __shfl_up(incl, o); if (ln >= o) incl += u; }
    const int excl = incl - cnt;
    const int nE = __shfl(incl, G_ROWS - 1);

    {
        const char* gsrc = (const char*)(rec + (size_t)rowbase * CAP);
        GLOAD16(gsrc + ln * 16, (char*)&idb[wv][0]);
        GLOAD16(gsrc + 1024 + ln * 16, (char*)&idb[wv][0] + 1024);
    }
    asm volatile("s_waitcnt vmcnt(0)" ::: "memory");
    __builtin_amdgcn_sched_barrier(0);

    float4 ae = make_float4(0.f, 0.f, 0.f, 0.f);
    float4 ax = make_float4(0.f, 0.f, 0.f, 0.f);
    int consRow = 0;
    int consEnd = __shfl(incl, 0);
    int issRow = 0;
    int issEnd = consEnd;

    // per-row results held in registers (wave-uniform switch -> static names, rule #20 safe)
    uint2 aeP0, aeP1, aeP2, aeP3, aeP4, aeP5, aeP6, aeP7;
    uint2 axP0, axP1, axP2, axP3, axP4, axP5, axP6, axP7;

    auto packbf = [](float4 v) {
        uint2 r;
        r.x = (unsigned)f2bf(v.x) | ((unsigned)f2bf(v.y) << 16);
        r.y = (unsigned)f2bf(v.z) | ((unsigned)f2bf(v.w) << 16);
        return r;
    };

    auto flush = [&]() {
        uint2 pe = packbf(ae), px = packbf(ax);
        switch (consRow) {
            case 0: aeP0 = pe; axP0 = px; break;
            case 1: aeP1 = pe; axP1 = px; break;
            case 2: aeP2 = pe; axP2 = px; break;
            case 3: aeP3 = pe; axP3 = px; break;
            case 4: aeP4 = pe; axP4 = px; break;
            case 5: aeP5 = pe; axP5 = px; break;
            case 6: aeP6 = pe; axP6 = px; break;
            default: aeP7 = pe; axP7 = px; break;
        }
        ae = make_float4(0.f, 0.f, 0.f, 0.f);
        ax = make_float4(0.f, 0.f, 0.f, 0.f);
    };

    auto issue = [&](int ci) {                   // chunk = 2 edges = 3 GLOADs (exact count)
        int buf = ci & 1;
        int sid[2] = {0, 0}, eid[2] = {0, 0};
#pragma unroll
        for (int t = 0; t < 2; ++t) {
            int ja = ci * 2 + t;
            if (ja < nE) {
                while (ja >= issEnd) { ++issRow; issEnd = __shfl(incl, issRow); }
                int st = __shfl(excl, issRow);
                int2 v = idb[wv][issRow * CAP + (ja - st)];
                eid[t] = v.x; sid[t] = v.y;
            }
        }
        GLOAD16NT(edge_feats + (size_t)eid[0] * D_IN + ln * 4, &fbe[wv][buf][0][0]);
        GLOAD16NT(edge_feats + (size_t)eid[1] * D_IN + ln * 4, &fbe[wv][buf][1][0]);
        int sidt = (ln < 32) ? sid[0] : sid[1];
        GLOAD16((const char*)Xs + (size_t)sidt * 512 + (ln & 31) * 16, (char*)&sxb[wv][buf][0]);
    };

    const int nCh = (nE + 1) >> 1;
    issue(0); issue(1);
    for (int ci = 0; ci < nCh; ++ci) {
        asm volatile("s_waitcnt vmcnt(3)" ::: "memory");   // chunk ci landed; ci+1 in flight
        __builtin_amdgcn_sched_barrier(0);
        int buf = ci & 1;
#pragma unroll
        for (int t = 0; t < 2; ++t) {
            int ja = ci * 2 + t;
            if (ja >= nE) break;                           // uniform
            while (ja >= consEnd) {                        // row boundary (uniform)
                flush();
                ++consRow;
                consEnd = __shfl(incl, consRow);
            }
            float4 ve = *reinterpret_cast<const float4*>(&fbe[wv][buf][t][ln * 4]);
            ushort4 vs = *reinterpret_cast<const ushort4*>((const char*)&sxb[wv][buf][0] + t * 512 + ln * 8);
            ae.x += ve.x; ae.y += ve.y; ae.z += ve.z; ae.w += ve.w;
            ax.x += bf2f(vs.x); ax.y += bf2f(vs.y); ax.z += bf2f(vs.z); ax.w += bf2f(vs.w);
        }
        issue(ci + 2);
    }
    asm volatile("s_waitcnt vmcnt(0)" ::: "memory");       // drain all in-flight LDS writes
    __builtin_amdgcn_sched_barrier(0);
    while (consRow < G_ROWS) { flush(); ++consRow; }

    __syncthreads();                                       // all waves done with phase-1 buffers

    // ---- regs -> LDS: AsL row R at (R>>1)*1024 + (R&1)*512, granule g^(R&7); SxL row-major ----
    {
#define WRROW(r, pe, px) {                                                            \
        int R = wv * G_ROWS + (r);                                                    \
        int gsw = ((ln >> 1) ^ (R & 7));                                              \
        *reinterpret_cast<uint2*>((char*)AsL + (R >> 1) * 1024 + (R & 1) * 512        \
                                  + gsw * 16 + (ln & 1) * 8) = pe;                    \
        *reinterpret_cast<uint2*>((char*)SxL + R * 512 + ln * 8) = px; }
        WRROW(0, aeP0, axP0); WRROW(1, aeP1, axP1); WRROW(2, aeP2, axP2); WRROW(3, aeP3, axP3);
        WRROW(4, aeP4, axP4); WRROW(5, aeP5, axP5); WRROW(6, aeP6, axP6); WRROW(7, aeP7, axP7);
#undef WRROW
    }
    __syncthreads();

    // ---- GEMM: out32x256 = AsL @ We (K=256) + SxL, *norm + bias ----
    const int lrow = ln & 15;
    const int lgrp = ln >> 4;

    f32x4 acc[2][4];
#pragma unroll
    for (int m = 0; m < 2; ++m)
#pragma unroll
        for (int n = 0; n < 4; ++n) acc[m][n] = (f32x4)(0.0f);

#pragma unroll
    for (int kk = 0; kk < 8; ++kk) {
        bf16x8 A[2];
#pragma unroll
        for (int m = 0; m < 2; ++m) {
            int r = m * 16 + lrow;
            int dg = (kk * 4 + lgrp) ^ (r & 7);
            A[m] = *reinterpret_cast<const bf16x8*>(
                (const char*)AsL + (r >> 1) * 1024 + (r & 1) * 512 + dg * 16);
        }
#pragma unroll
        for (int n = 0; n < 4; ++n) {
            int nt = wv * 4 + n;
            bf16x8 B = *reinterpret_cast<const bf16x8*>(&wfe[(((size_t)nt * 8 + kk) * 64 + ln) * 8]);
#pragma unroll
            for (int m = 0; m < 2; ++m)
                acc[m][n] = __builtin_amdgcn_mfma_f32_16x16x32_bf16(A[m], B, acc[m][n], 0, 0, 0);
        }
    }

    float bias_r[4];
#pragma unroll
    for (int n = 0; n < 4; ++n) bias_r[n] = bias[wv * 64 + n * 16 + lrow];

#pragma unroll
    for (int m = 0; m < 2; ++m) {
#pragma unroll
        for (int j = 0; j < 4; ++j) {
            int lr = m * 16 + lgrp * 4 + j;
            int r = bbase + lr;
            if (r < n_dst) {
                int dg = cursor[r];
                float nv = (dg > 0) ? rsqrtf((float)dg) : 0.0f;
#pragma unroll
                for (int n = 0; n < 4; ++n) {
                    int col = wv * 64 + n * 16 + lrow;
                    float sxv = bf2f(SxL[lr * 256 + col]);
                    out[(size_t)r * D_OUT + col] = (acc[m][n][j] + sxv) * nv + bias_r[n];
                }
            }
        }
    }
}

extern "C" void kernel_launch(void* const* d_in, const int* in_sizes, int n_in,
                              void* d_out, int out_size, void* d_ws, size_t ws_size,
                              hipStream_t stream) {
    const float* src_feats  = (const float*)d_in[0];
    const float* edge_feats = (const float*)d_in[1];
    const int*   src_idx    = (const int*)d_in[2];
    const int*   dst_idx    = (const int*)d_in[3];
    const float* weights    = (const float*)d_in[4];
    const float* h_bias     = (const float*)d_in[5];

    const int E     = in_sizes[2];
    const int n_src = in_sizes[0] / D_IN;
    const int n_dst = out_size / D_OUT;
    float* out = (float*)d_out;

    char* ws = (char*)d_ws;
    size_t xs_bytes = (size_t)n_src * D_OUT * 2;                       // 25.6 MB
    unsigned short* Xs  = (unsigned short*)ws;
    unsigned short* wfs = (unsigned short*)(ws + xs_bytes);            // 128 KB
    unsigned short* wfe = wfs + 65536;                                 // 128 KB
    int2* rec    = (int2*)(ws + xs_bytes + 262144);                    // n_dst*CAP*8 + pad
    size_t rec_bytes = (size_t)n_dst * CAP * 8 + 4096;
    int* cursor  = (int*)(ws + xs_bytes + 262144 + rec_bytes);

    const int ZB = (n_dst + 255) / 256;
    const int SB = (E / 2 + 255) / 256;
    const int XB = (n_src + 31) / 32;
    const int NB = (n_dst + 4 * G_ROWS - 1) / (4 * G_ROWS);

    zero_wfrag_kernel<<<ZB + 64, 256, 0, stream>>>(cursor, n_dst, ZB, weights, wfs, wfe);
    combo_kernel<<<SB + XB, 256, 0, stream>>>(dst_idx, src_idx, cursor, rec, E, SB,
                                              src_feats, wfs, Xs, n_src);
    agg_gemm_kernel<<<NB, 256, 0, stream>>>(Xs, edge_feats, rec, cursor, wfe, h_bias, out, n_dst);
}

// Round 14
// 194.666 us; speedup vs baseline: 1.0378x; 1.0378x over previous
//
#include <hip/hip_runtime.h>

typedef __attribute__((ext_vector_type(8))) short bf16x8;
typedef __attribute__((ext_vector_type(4))) float f32x4;

#define D_IN 256
#define D_OUT 256
#define G_ROWS 8           // dst rows per wave in agg
#define CAP 32             // edge slots per dst row (max deg ~22 for Poisson(8))

static __device__ __forceinline__ unsigned short f2bf(float f) {
    union { float f; unsigned int u; } x; x.f = f;
    unsigned int r = (x.u + 0x7FFFu + ((x.u >> 16) & 1u)) >> 16;
    return (unsigned short)r;
}
static __device__ __forceinline__ float bf2f(unsigned short u) {
    union { unsigned int i; float f; } x; x.i = ((unsigned int)u) << 16; return x.f;
}

// async global->LDS: lds dest = UNIFORM base (HW adds lane*16); global src = per-lane
#define GLOAD16(gp, lp) __builtin_amdgcn_global_load_lds(                    \
    (const __attribute__((address_space(1))) void*)(gp),                     \
    (__attribute__((address_space(3))) void*)(lp), 16, 0, 0)
// non-temporal (aux=2): evict-first, keeps L3 for Xs reuse
#define GLOAD16NT(gp, lp) __builtin_amdgcn_global_load_lds(                  \
    (const __attribute__((address_space(1))) void*)(gp),                     \
    (__attribute__((address_space(3))) void*)(lp), 16, 0, 2)

// ---------------- zero cursor + pack BOTH W-half fragments ----------------
// wfrag layout (K=256 each): wf[((nt*8+kk)*64+l)*8+j] = bf16(W[s*256 + kk*32+(l>>4)*8+j][nt*16+(l&15)])
__global__ void zero_wfrag_kernel(int* __restrict__ cursor, int n, int zblocks,
                                  const float* __restrict__ W,
                                  unsigned short* __restrict__ wfs,
                                  unsigned short* __restrict__ wfe) {
    int b = blockIdx.x;
    if (b < zblocks) {
        int i = b * 256 + threadIdx.x;
        if (i < n) cursor[i] = 0;
        return;
    }
    int s = (b - zblocks) >> 5;                      // 0: Ws, 1: We
    int t = ((b - zblocks) & 31) * 256 + threadIdx.x; // 0..8191
    int l  = t & 63;
    int kk = (t >> 6) & 7;
    int nt = t >> 9;
    int c  = nt * 16 + (l & 15);
    int kb = s * 256 + kk * 32 + (l >> 4) * 8;
    union { unsigned short u[8]; uint4 v; } pk;
#pragma unroll
    for (int j = 0; j < 8; ++j) pk.u[j] = f2bf(W[(size_t)(kb + j) * D_OUT + c]);
    unsigned short* wf = s ? wfe : wfs;
    *reinterpret_cast<uint4*>(&wf[(size_t)t * 8]) = pk.v;
}

// ---------------- combo: bucket scatter (blocks < SB) + xs_gemm (rest) ----------------
// scatter: rec[d*CAP+p] = {edge_id, src_id}; cursor -> degrees
// xs_gemm: Xs[n_src x 256] = bf16(src_feats @ Ws), 32 rows/block, LDS-staged A with granule swizzle
__global__ __launch_bounds__(256) void combo_kernel(
    const int* __restrict__ dst, const int* __restrict__ src_idx,
    int* __restrict__ cursor, int2* __restrict__ rec, int E, int SB,
    const float* __restrict__ src_feats, const unsigned short* __restrict__ wfs,
    unsigned short* __restrict__ Xs, int n_src)
{
    __shared__ __align__(16) float As[32 * 256];   // 32 KB (xs part only)

    if (blockIdx.x < SB) {
        int e2 = (blockIdx.x * 256 + threadIdx.x) * 2;
        if (e2 + 1 < E) {
            int2 d = *reinterpret_cast<const int2*>(&dst[e2]);
            int2 s = *reinterpret_cast<const int2*>(&src_idx[e2]);
            int p0 = atomicAdd(&cursor[d.x], 1);
            if (p0 < CAP) rec[(size_t)d.x * CAP + p0] = make_int2(e2, s.x);
            int p1 = atomicAdd(&cursor[d.y], 1);
            if (p1 < CAP) rec[(size_t)d.y * CAP + p1] = make_int2(e2 + 1, s.y);
        } else if (e2 < E) {
            int d = dst[e2];
            int p = atomicAdd(&cursor[d], 1);
            if (p < CAP) rec[(size_t)d * CAP + p] = make_int2(e2, src_idx[e2]);
        }
        return;
    }

    const int wv = threadIdx.x >> 6;
    const int ln = threadIdx.x & 63;
    const int lrow = ln & 15;
    const int lgrp = ln >> 4;
    const int base = (blockIdx.x - SB) * 32;

    // stage 32 fp32 rows (1 KB each = 1 GLOAD16), 16B-granule XOR swizzle
#pragma unroll
    for (int q = 0; q < 8; ++q) {
        int r = q * 4 + wv;
        int gr = base + r; if (gr >= n_src) gr = n_src - 1;
        GLOAD16(src_feats + (size_t)gr * D_IN + ((ln ^ (r & 7)) * 4),
                (char*)As + r * 1024);
    }
    asm volatile("s_waitcnt vmcnt(0)" ::: "memory");
    __builtin_amdgcn_s_barrier();
    __builtin_amdgcn_sched_barrier(0);

    f32x4 acc[2][4];
#pragma unroll
    for (int m = 0; m < 2; ++m)
#pragma unroll
        for (int n = 0; n < 4; ++n) acc[m][n] = (f32x4)(0.0f);

#pragma unroll
    for (int kk = 0; kk < 8; ++kk) {
        bf16x8 A[2];
#pragma unroll
        for (int m = 0; m < 2; ++m) {
            int r = m * 16 + lrow;
            int pi = kk * 4 + lgrp;
            int g0 = (2 * pi) ^ (r & 7);
            int g1 = (2 * pi + 1) ^ (r & 7);
            float4 f0 = *reinterpret_cast<const float4*>((const char*)As + r * 1024 + g0 * 16);
            float4 f1 = *reinterpret_cast<const float4*>((const char*)As + r * 1024 + g1 * 16);
            union { unsigned short u[8]; bf16x8 v; } pk;
            pk.u[0] = f2bf(f0.x); pk.u[1] = f2bf(f0.y); pk.u[2] = f2bf(f0.z); pk.u[3] = f2bf(f0.w);
            pk.u[4] = f2bf(f1.x); pk.u[5] = f2bf(f1.y); pk.u[6] = f2bf(f1.z); pk.u[7] = f2bf(f1.w);
            A[m] = pk.v;
        }
#pragma unroll
        for (int n = 0; n < 4; ++n) {
            int nt = wv * 4 + n;
            bf16x8 B = *reinterpret_cast<const bf16x8*>(&wfs[(((size_t)nt * 8 + kk) * 64 + ln) * 8]);
#pragma unroll
            for (int m = 0; m < 2; ++m)
                acc[m][n] = __builtin_amdgcn_mfma_f32_16x16x32_bf16(A[m], B, acc[m][n], 0, 0, 0);
        }
    }

#pragma unroll
    for (int m = 0; m < 2; ++m) {
#pragma unroll
        for (int j = 0; j < 4; ++j) {
            int r = base + m * 16 + lgrp * 4 + j;
            if (r < n_src) {
#pragma unroll
                for (int n = 0; n < 4; ++n)
                    Xs[(size_t)r * D_OUT + wv * 64 + n * 16 + lrow] = f2bf(acc[m][n][j]);
            }
        }
    }
}

// ---------------- aggregation: sums Xs rows (bf16, L3-hot) + edge rows (fp32, NT stream) ----------------
// Per 2-edge chunk: 3 GLOAD16 (2 edge rows + 1 combined src-pair row). 2-deep pipeline, vmcnt(3).
// Tail chunks issue dummy loads (row 0) to keep the outstanding count exact -- do not predicate away.
__global__ __launch_bounds__(256) void agg_kernel(
    const unsigned short* __restrict__ Xs,
    const float* __restrict__ edge_feats,
    const int2* __restrict__ rec,
    const int* __restrict__ cursor,
    unsigned short* __restrict__ Ae,
    unsigned short* __restrict__ Sx,
    int n_dst)
{
    __shared__ __align__(16) float fbe[4][2][2][D_IN];        // 16 KB: edge rows
    __shared__ __align__(16) unsigned short sxb[4][2][512];   // 8 KB: src-pair rows (bf16)
    __shared__ __align__(16) int2 idb[4][G_ROWS * CAP];       // 8 KB

    const int wv = threadIdx.x >> 6;
    const int ln = threadIdx.x & 63;
    const int rowbase = (blockIdx.x * 4 + wv) * G_ROWS;

    int cnt = 0;
    if (ln < G_ROWS) {
        int i = rowbase + ln;
        if (i < n_dst) { cnt = cursor[i]; if (cnt > CAP) cnt = CAP; }
    }
    int incl = cnt;
#pragma unroll
    for (int o = 1; o < 64; o <<= 1) { int u = __shfl_up(incl, o); if (ln >= o) incl += u; }
    const int excl = incl - cnt;
    const int nE = __shfl(incl, G_ROWS - 1);

    {
        const char* gsrc = (const char*)(rec + (size_t)rowbase * CAP);
        GLOAD16(gsrc + ln * 16, (char*)&idb[wv][0]);
        GLOAD16(gsrc + 1024 + ln * 16, (char*)&idb[wv][0] + 1024);
    }
    asm volatile("s_waitcnt vmcnt(0)" ::: "memory");
    __builtin_amdgcn_sched_barrier(0);

    float4 ae = make_float4(0.f, 0.f, 0.f, 0.f);   // edge accum, cols [4ln,4ln+4)
    float4 ax = make_float4(0.f, 0.f, 0.f, 0.f);   // src  accum, cols [4ln,4ln+4)
    int consRow = 0;
    int consEnd = __shfl(incl, 0);
    int issRow = 0;
    int issEnd = consEnd;

    auto flush = [&]() {
        int gr = rowbase + consRow;
        if (gr < n_dst) {
            ushort4 pe, px;
            pe.x = f2bf(ae.x); pe.y = f2bf(ae.y); pe.z = f2bf(ae.z); pe.w = f2bf(ae.w);
            px.x = f2bf(ax.x); px.y = f2bf(ax.y); px.z = f2bf(ax.z); px.w = f2bf(ax.w);
            *reinterpret_cast<ushort4*>(&Ae[(size_t)gr * D_OUT + ln * 4]) = pe;
            *reinterpret_cast<ushort4*>(&Sx[(size_t)gr * D_OUT + ln * 4]) = px;
        }
        ae = make_float4(0.f, 0.f, 0.f, 0.f);
        ax = make_float4(0.f, 0.f, 0.f, 0.f);
    };

    auto issue = [&](int ci) {                   // chunk = 2 edges = 3 GLOADs (exact count)
        int buf = ci & 1;
        int sid[2] = {0, 0}, eid[2] = {0, 0};
#pragma unroll
        for (int t = 0; t < 2; ++t) {
            int ja = ci * 2 + t;
            if (ja < nE) {
                while (ja >= issEnd) { ++issRow; issEnd = __shfl(incl, issRow); }
                int st = __shfl(excl, issRow);
                int2 v = idb[wv][issRow * CAP + (ja - st)];
                eid[t] = v.x; sid[t] = v.y;
            }
        }
        GLOAD16NT(edge_feats + (size_t)eid[0] * D_IN + ln * 4, &fbe[wv][buf][0][0]);
        GLOAD16NT(edge_feats + (size_t)eid[1] * D_IN + ln * 4, &fbe[wv][buf][1][0]);
        int sidt = (ln < 32) ? sid[0] : sid[1];
        GLOAD16((const char*)Xs + (size_t)sidt * 512 + (ln & 31) * 16, (char*)&sxb[wv][buf][0]);
    };

    const int nCh = (nE + 1) >> 1;
    issue(0); issue(1);
    for (int ci = 0; ci < nCh; ++ci) {
        asm volatile("s_waitcnt vmcnt(3)" ::: "memory");   // chunk ci landed; ci+1 in flight
        __builtin_amdgcn_sched_barrier(0);
        int buf = ci & 1;
#pragma unroll
        for (int t = 0; t < 2; ++t) {
            int ja = ci * 2 + t;
            if (ja >= nE) break;                           // uniform
            while (ja >= consEnd) {                        // row boundary (uniform)
                flush();
                ++consRow;
                consEnd = __shfl(incl, consRow);
            }
            float4 ve = *reinterpret_cast<const float4*>(&fbe[wv][buf][t][ln * 4]);
            ushort4 vs = *reinterpret_cast<const ushort4*>((const char*)&sxb[wv][buf][0] + t * 512 + ln * 8);
            ae.x += ve.x; ae.y += ve.y; ae.z += ve.z; ae.w += ve.w;
            ax.x += bf2f(vs.x); ax.y += bf2f(vs.y); ax.z += bf2f(vs.z); ax.w += bf2f(vs.w);
        }
        issue(ci + 2);
    }
    asm volatile("s_waitcnt vmcnt(0)" ::: "memory");       // drain before exit
    __builtin_amdgcn_sched_barrier(0);
    while (consRow < G_ROWS) { flush(); ++consRow; }
}

// ---------------- GEMM: out = (Sx + Ae @ We) * norm + bias, K=256, 32 rows/block ----------------
__global__ __launch_bounds__(256) void gemm_kernel(
    const unsigned short* __restrict__ Ae,
    const unsigned short* __restrict__ Sx,
    const unsigned short* __restrict__ wfe,
    const int* __restrict__ cursor,
    const float* __restrict__ bias,
    float* __restrict__ out,
    int n_dst)
{
    // As: 16 row-pairs x 1KB; row 2p at [0,512), row 2p+1 at [512,1024); granules XOR-swizzled by (row&7)
    __shared__ __align__(16) unsigned short As[32 * 256];   // 16 KB

    const int wv = threadIdx.x >> 6;
    const int ln = threadIdx.x & 63;
    const int lrow = ln & 15;
    const int lgrp = ln >> 4;
    const int base = blockIdx.x * 32;

#pragma unroll
    for (int q = 0; q < 4; ++q) {
        int p = q * 4 + wv;                    // row-pair 0..15
        int rr = 2 * p + (ln >> 5);            // local row
        int gr = base + rr; if (gr >= n_dst) gr = n_dst - 1;
        GLOAD16((const char*)Ae + (size_t)gr * 512 + (size_t)(((ln & 31) ^ (rr & 7)) * 16),
                (char*)As + p * 1024);
    }
    asm volatile("s_waitcnt vmcnt(0)" ::: "memory");
    __builtin_amdgcn_s_barrier();
    __builtin_amdgcn_sched_barrier(0);

    f32x4 acc[2][4];
#pragma unroll
    for (int m = 0; m < 2; ++m)
#pragma unroll
        for (int n = 0; n < 4; ++n) acc[m][n] = (f32x4)(0.0f);

#pragma unroll
    for (int kk = 0; kk < 8; ++kk) {
        bf16x8 A[2];
#pragma unroll
        for (int m = 0; m < 2; ++m) {
            int r = m * 16 + lrow;
            int dg = (kk * 4 + lgrp) ^ (r & 7);
            A[m] = *reinterpret_cast<const bf16x8*>(
                (const char*)As + (r >> 1) * 1024 + (r & 1) * 512 + dg * 16);
        }
#pragma unroll
        for (int n = 0; n < 4; ++n) {
            int nt = wv * 4 + n;
            bf16x8 B = *reinterpret_cast<const bf16x8*>(&wfe[(((size_t)nt * 8 + kk) * 64 + ln) * 8]);
#pragma unroll
            for (int m = 0; m < 2; ++m)
                acc[m][n] = __builtin_amdgcn_mfma_f32_16x16x32_bf16(A[m], B, acc[m][n], 0, 0, 0);
        }
    }

    float bias_r[4];
#pragma unroll
    for (int n = 0; n < 4; ++n) bias_r[n] = bias[wv * 64 + n * 16 + lrow];

#pragma unroll
    for (int m = 0; m < 2; ++m) {
#pragma unroll
        for (int j = 0; j < 4; ++j) {
            int r = base + m * 16 + lgrp * 4 + j;
            if (r < n_dst) {
                int dg = cursor[r];
                float nv = (dg > 0) ? rsqrtf((float)dg) : 0.0f;
#pragma unroll
                for (int n = 0; n < 4; ++n) {
                    int col = wv * 64 + n * 16 + lrow;
                    float sxv = bf2f(Sx[(size_t)r * D_OUT + col]);
                    out[(size_t)r * D_OUT + col] = (acc[m][n][j] + sxv) * nv + bias_r[n];
                }
            }
        }
    }
}

extern "C" void kernel_launch(void* const* d_in, const int* in_sizes, int n_in,
                              void* d_out, int out_size, void* d_ws, size_t ws_size,
                              hipStream_t stream) {
    const float* src_feats  = (const float*)d_in[0];
    const float* edge_feats = (const float*)d_in[1];
    const int*   src_idx    = (const int*)d_in[2];
    const int*   dst_idx    = (const int*)d_in[3];
    const float* weights    = (const float*)d_in[4];
    const float* h_bias     = (const float*)d_in[5];

    const int E     = in_sizes[2];
    const int n_src = in_sizes[0] / D_IN;
    const int n_dst = out_size / D_OUT;
    float* out = (float*)d_out;

    char* ws = (char*)d_ws;
    size_t xs_bytes = (size_t)n_src * D_OUT * 2;                       // 25.6 MB
    size_t ad_bytes = (size_t)n_dst * D_OUT * 2;                       // 25.6 MB
    unsigned short* Xs  = (unsigned short*)ws;
    unsigned short* Ae  = (unsigned short*)(ws + xs_bytes);
    unsigned short* Sx  = (unsigned short*)(ws + xs_bytes + ad_bytes);
    unsigned short* wfs = (unsigned short*)(ws + xs_bytes + 2 * ad_bytes);            // 128 KB
    unsigned short* wfe = wfs + 65536;                                                 // 128 KB
    int2* rec    = (int2*)(ws + xs_bytes + 2 * ad_bytes + 262144);     // n_dst*CAP*8 + pad
    size_t rec_bytes = (size_t)n_dst * CAP * 8 + 4096;
    int* cursor  = (int*)(ws + xs_bytes + 2 * ad_bytes + 262144 + rec_bytes);

    const int ZB = (n_dst + 255) / 256;
    const int SB = (E / 2 + 255) / 256;
    const int XB = (n_src + 31) / 32;
    const int NB = (n_dst + 4 * G_ROWS - 1) / (4 * G_ROWS);

    zero_wfrag_kernel<<<ZB + 64, 256, 0, stream>>>(cursor, n_dst, ZB, weights, wfs, wfe);
    combo_kernel<<<SB + XB, 256, 0, stream>>>(dst_idx, src_idx, cursor, rec, E, SB,
                                              src_feats, wfs, Xs, n_src);
    agg_kernel<<<NB, 256, 0, stream>>>(Xs, edge_feats, rec, cursor, Ae, Sx, n_dst);
    gemm_kernel<<<NB, 256, 0, stream>>>(Ae, Sx, wfe, cursor, h_bias, out, n_dst);
}